// Round 2
// baseline (547.865 us; speedup 1.0000x reference)
//
#include <hip/hip_runtime.h>
#include <stdint.h>

// ---------------------------------------------------------------------------
// JAX threefry2x32 (20 rounds), bit-exact port of jax/_src/prng.py
// ---------------------------------------------------------------------------
static __host__ __device__ inline uint32_t rotl32(uint32_t x, int r) {
  return (x << r) | (x >> (32 - r));
}

static __host__ __device__ inline void tf2x32(uint32_t k0, uint32_t k1,
                                              uint32_t x0, uint32_t x1,
                                              uint32_t& o0, uint32_t& o1) {
  uint32_t k2 = k0 ^ k1 ^ 0x1BD11BDAu;
#define TFR(a) { x0 += x1; x1 = rotl32(x1, a); x1 ^= x0; }
  x0 += k0; x1 += k1;
  TFR(13) TFR(15) TFR(26) TFR(6)
  x0 += k1; x1 += k2 + 1u;
  TFR(17) TFR(29) TFR(16) TFR(24)
  x0 += k2; x1 += k0 + 2u;
  TFR(13) TFR(15) TFR(26) TFR(6)
  x0 += k0; x1 += k1 + 3u;
  TFR(17) TFR(29) TFR(16) TFR(24)
  x0 += k1; x1 += k2 + 4u;
  TFR(13) TFR(15) TFR(26) TFR(6)
  x0 += k2; x1 += k0 + 5u;
#undef TFR
  o0 = x0; o1 = x1;
}

// partitionable random_bits (bit_width 32): counter = 64-bit flat index
// (hi word 0 for N < 2^32); output = o0 ^ o1 (the "fold").
static __device__ inline uint32_t fold_bits(uint32_t k0, uint32_t k1, uint32_t ctr) {
  uint32_t a, b;
  tf2x32(k0, k1, 0u, ctr, a, b);
  return a ^ b;
}

// Partial-sort cutoff: only elements whose 23-bit sort mantissa m < CUT are
// donor candidates. Expected candidates = 0.125*N ~ 4.19M >= R ~ 3.36M with
// ~440 sigma margin (data is deterministic: fixed seeds).
#define CUT      (1u << 20)
#define SORT_CAP (6u * 1024u * 1024u)   // sortedIdx capacity (entries)

// ---------------------------------------------------------------------------
// Pass 1 (fused): bernoulli mask + per-block repl counts + candidate histogram
// Block covers 4096 elements (16 x 256).
// ---------------------------------------------------------------------------
__global__ void k_pass1(const float* __restrict__ x, uint64_t* __restrict__ mask,
                        uint32_t* __restrict__ rsums, uint32_t* __restrict__ buckets,
                        uint32_t bk0, uint32_t bk1, uint32_t sk0, uint32_t sk1, int n) {
  __shared__ uint32_t wcnt[4];
  int tid = threadIdx.x, lane = tid & 63, wid = tid >> 6;
  int base = blockIdx.x * 4096;
  uint32_t cnt = 0;
  for (int k = 0; k < 16; k++) {
    int i = base + k * 256 + tid;
    bool r = false;
    if (i < n) {
      float xv = x[i];
      bool nonpad = (xv != 0.0f);
      // bernoulli
      uint32_t bb = fold_bits(bk0, bk1, (uint32_t)i);
      float u = __uint_as_float((bb >> 9) | 0x3f800000u) - 1.0f;
      r = (u < 0.1f) && nonpad;
      // shuffle-key histogram (candidates only)
      uint32_t m = fold_bits(sk0, sk1, (uint32_t)i) >> 9;
      if (nonpad && m < CUT) atomicAdd((unsigned int*)&buckets[m], 1u);
    }
    unsigned long long ball = __ballot(r);
    int wbase = base + k * 256 + wid * 64;
    if (lane == 0 && wbase < n) mask[wbase / 64] = (uint64_t)ball;
    cnt += r ? 1u : 0u;
  }
  for (int d = 32; d >= 1; d >>= 1) cnt += __shfl_down(cnt, d, 64);
  if (lane == 0) wcnt[wid] = cnt;
  __syncthreads();
  if (tid == 0) rsums[blockIdx.x] = wcnt[0] + wcnt[1] + wcnt[2] + wcnt[3];
}

// ---------------------------------------------------------------------------
// Scan helpers: chunk sums -> single-block scan -> per-chunk apply
// ---------------------------------------------------------------------------
__global__ void k_chunksum(const uint32_t* __restrict__ data, uint32_t* __restrict__ sums, int n) {
  __shared__ uint32_t wsum[4];
  int tid = threadIdx.x, lane = tid & 63, wid = tid >> 6;
  int base = blockIdx.x * 4096;
  uint32_t s = 0;
  for (int k = 0; k < 16; k++) {
    int i = base + k * 256 + tid;
    if (i < n) s += data[i];
  }
  for (int d = 32; d >= 1; d >>= 1) s += __shfl_down(s, d, 64);
  if (lane == 0) wsum[wid] = s;
  __syncthreads();
  if (tid == 0) sums[blockIdx.x] = wsum[0] + wsum[1] + wsum[2] + wsum[3];
}

__global__ void k_scan_single(uint32_t* __restrict__ data, int n) {
  __shared__ uint32_t wsum[4];
  int tid = threadIdx.x, lane = tid & 63, wid = tid >> 6;
  uint32_t running = 0;
  for (int base = 0; base < n; base += 256) {
    int i = base + tid;
    uint32_t v = (i < n) ? data[i] : 0u;
    uint32_t incl = v;
    for (int d = 1; d < 64; d <<= 1) {
      uint32_t t = __shfl_up(incl, (unsigned)d, 64);
      if (lane >= d) incl += t;
    }
    if (lane == 63) wsum[wid] = incl;
    __syncthreads();
    uint32_t woff = 0, tot = 0;
    for (int w = 0; w < 4; w++) { uint32_t s = wsum[w]; if (w < wid) woff += s; tot += s; }
    if (i < n) data[i] = running + woff + (incl - v);
    running += tot;
    __syncthreads();
  }
}

__global__ void k_scan_apply(uint32_t* __restrict__ data, const uint32_t* __restrict__ sums, int n) {
  __shared__ uint32_t wsum[4];
  int tid = threadIdx.x, lane = tid & 63, wid = tid >> 6;
  int base = blockIdx.x * 4096;
  uint32_t running = sums[blockIdx.x];
  for (int k = 0; k < 16; k++) {
    int i = base + k * 256 + tid;
    uint32_t v = (i < n) ? data[i] : 0u;
    uint32_t incl = v;
    for (int d = 1; d < 64; d <<= 1) {
      uint32_t t = __shfl_up(incl, (unsigned)d, 64);
      if (lane >= d) incl += t;
    }
    if (lane == 63) wsum[wid] = incl;
    __syncthreads();
    uint32_t woff = 0, tot = 0;
    for (int w = 0; w < 4; w++) { uint32_t s = wsum[w]; if (w < wid) woff += s; tot += s; }
    if (i < n) data[i] = running + woff + (incl - v);
    running += tot;
    __syncthreads();
  }
}

// ---------------------------------------------------------------------------
// Scatter candidate indices into buckets (intra-bucket order fixed afterwards)
// ---------------------------------------------------------------------------
__global__ void k_scatter(const float* __restrict__ x, uint32_t* __restrict__ cursors,
                          uint32_t* __restrict__ sortedIdx, uint32_t sk0, uint32_t sk1, int n) {
  int i = blockIdx.x * blockDim.x + threadIdx.x;
  if (i >= n) return;
  if (x[i] == 0.0f) return;
  uint32_t m = fold_bits(sk0, sk1, (uint32_t)i) >> 9;
  if (m >= CUT) return;
  uint32_t pos = atomicAdd((unsigned int*)&cursors[m], 1u);
  if (pos < SORT_CAP) sortedIdx[pos] = (uint32_t)i;
}

// ---------------------------------------------------------------------------
// Per-bucket insertion sort by index -> stable order (avg bucket size ~4)
// After scatter, cursors[b] = end of bucket b; start = cursors[b-1] (or 0).
// ---------------------------------------------------------------------------
__global__ void k_bucket_sort(const uint32_t* __restrict__ cursors,
                              uint32_t* __restrict__ sortedIdx, uint32_t nb) {
  uint32_t b = blockIdx.x * blockDim.x + threadIdx.x;
  if (b >= nb) return;
  uint32_t end = cursors[b];
  uint32_t start = (b == 0) ? 0u : cursors[b - 1];
  if (end > SORT_CAP) end = SORT_CAP;
  if (start > SORT_CAP) start = SORT_CAP;
  if (end - start <= 1u) return;
  for (uint32_t u = start + 1; u < end; u++) {
    uint32_t v = sortedIdx[u];
    uint32_t w = u;
    while (w > start && sortedIdx[w - 1] > v) { sortedIdx[w] = sortedIdx[w - 1]; w--; }
    sortedIdx[w] = v;
  }
}

// ---------------------------------------------------------------------------
// Final: out[i] = repl ? x[sortedIdx[rank]] : x[i]
// ---------------------------------------------------------------------------
__global__ void k_final(const float* __restrict__ x, const uint64_t* __restrict__ mask,
                        const uint32_t* __restrict__ rsums, const uint32_t* __restrict__ sortedIdx,
                        float* __restrict__ out, int n) {
  __shared__ uint32_t wcnt[4];
  int tid = threadIdx.x, lane = tid & 63, wid = tid >> 6;
  int base = blockIdx.x * 4096;
  uint32_t running = rsums[blockIdx.x];
  for (int k = 0; k < 16; k++) {
    int i = base + k * 256 + tid;
    int wbase = base + k * 256 + wid * 64;
    uint64_t word = (wbase < n) ? mask[wbase / 64] : 0ull;
    bool r = (word >> lane) & 1ull;
    uint32_t inword = (uint32_t)__popcll(word & ((1ull << lane) - 1ull));
    uint32_t wtot = (uint32_t)__popcll(word);
    if (lane == 0) wcnt[wid] = wtot;
    __syncthreads();
    uint32_t woff = 0, tot = 0;
    for (int w = 0; w < 4; w++) { uint32_t s = wcnt[w]; if (w < wid) woff += s; tot += s; }
    if (i < n) {
      float o = x[i];
      if (r) {
        uint32_t rank = running + woff + inword;
        o = x[sortedIdx[rank]];
      }
      out[i] = o;
    }
    running += tot;
    __syncthreads();
  }
}

// ---------------------------------------------------------------------------
extern "C" void kernel_launch(void* const* d_in, const int* in_sizes, int n_in,
                              void* d_out, int out_size, void* d_ws, size_t ws_size,
                              hipStream_t stream) {
  const float* x = (const float*)d_in[0];
  float* out = (float*)d_out;
  int n = in_sizes[0];

  // Host-side key derivation (foldlike split of key(42)):
  //   k_bern = threefry((0,42),(0,0)), k_shuf = threefry((0,42),(0,1))
  uint32_t bk0, bk1, sk0, sk1;
  tf2x32(0u, 42u, 0u, 0u, bk0, bk1);
  tf2x32(0u, 42u, 0u, 1u, sk0, sk1);

  // workspace layout (~32 MB total)
  size_t off = 0;
  auto alloc = [&](size_t bytes) -> void* {
    void* p = (uint8_t*)d_ws + off;
    off += (bytes + 255) & ~(size_t)255;
    return p;
  };
  uint32_t* buckets   = (uint32_t*)alloc((size_t)CUT * 4);                    // 4 MB
  uint32_t* bsums     = (uint32_t*)alloc((size_t)256 * 4);
  uint32_t* rsums     = (uint32_t*)alloc((size_t)((n + 4095) / 4096) * 4);    // 32 KB
  uint64_t* mask      = (uint64_t*)alloc((size_t)((n + 63) / 64) * 8);        // 4 MB
  uint32_t* sortedIdx = (uint32_t*)alloc((size_t)SORT_CAP * 4);               // 24 MB
  (void)ws_size; (void)n_in; (void)out_size;

  int nThreadBlocks = (n + 255) / 256;
  int nChunksB = (int)(CUT / 4096);             // 256
  int nBlk4096 = (n + 4095) / 4096;             // 8192
  int nBucketBlocks = (int)(CUT / 256);         // 4096

  hipMemsetAsync(buckets, 0, (size_t)CUT * 4, stream);

  // fused: bernoulli mask + repl counts + candidate histogram
  k_pass1<<<nBlk4096, 256, 0, stream>>>(x, mask, rsums, buckets, bk0, bk1, sk0, sk1, n);

  // exclusive scan of buckets (counting sort offsets)
  k_chunksum<<<nChunksB, 256, 0, stream>>>(buckets, bsums, (int)CUT);
  k_scan_single<<<1, 256, 0, stream>>>(bsums, nChunksB);
  k_scan_apply<<<nChunksB, 256, 0, stream>>>(buckets, bsums, (int)CUT);

  // scatter candidates, then stabilize each bucket by index
  k_scatter<<<nThreadBlocks, 256, 0, stream>>>(x, buckets, sortedIdx, sk0, sk1, n);
  k_bucket_sort<<<nBucketBlocks, 256, 0, stream>>>(buckets, sortedIdx, CUT);

  // ranks + final gather
  k_scan_single<<<1, 256, 0, stream>>>(rsums, nBlk4096);
  k_final<<<nBlk4096, 256, 0, stream>>>(x, mask, rsums, sortedIdx, out, n);
}